// Round 6
// baseline (159.915 us; speedup 1.0000x reference)
//
#include <hip/hip_runtime.h>

#define B_PAT 32
#define RTOT 2048
#define NV 32
#define LMAX 1008
#define NTS 16
#define NIN 64    // K-padded feature width (from 34)
#define TLD 72    // feature tile LDS row stride (ushorts)
#define HW 128    // MLP width / hidden
#define LDSP 136  // LDS row stride for MLP bufs (ushorts)
#define NCH 16    // position-chunks per patient
#define CH 63     // positions per chunk
#define ELD 132   // enc LDS stride (floats)
#define RLD 136   // r LDS stride (floats)

// LDS union offsets (bytes): region0 = tile (9216 B) U bufB (17408 B);
// region1 = bufA (17408 B) U encs (33792 B). Lifetimes:
//   tile: written P0 copy, read layer0 | bufB: written layer1, read layer2
//   bufA: written layer0, read layer1  | encs: written layer2, read logits/wsum
#define SM_R0 0
#define SM_R1 17408
#define SM_TOTAL (17408 + 33792)

typedef __attribute__((ext_vector_type(8))) short short8;
typedef __attribute__((ext_vector_type(4))) float floatx4;

__device__ __forceinline__ ushort f2b(float f) {
  unsigned int x = __float_as_uint(f);
  unsigned int r = (x + 0x7FFFu + ((x >> 16) & 1u)) >> 16;
  return (ushort)r;
}
__device__ __forceinline__ unsigned int pack2(ushort lo, ushort hi) {
  return (unsigned int)lo | ((unsigned int)hi << 16);
}
__device__ __forceinline__ float tscale(int i) {
  return exp2f((float)i * (6.643856189774724f / 15.0f)); // 100^(i/15)
}

// ---------------------------------------------------------------------------
// kP: blocks 0..31 (512 thr) — per-patient prep: row scan -> pbase/lens,
// per-row times, FULL per-position bf16 feature rows -> feat_g (so kF never
// touches M/X/pbase/times or transcendentals), q-row fp32 GEMV chain -> r_all.
// blocks 32..34 — weight conversions to bf16 (W0 K-padded, W1, W2).
// ---------------------------------------------------------------------------
__global__ __launch_bounds__(512) void kP(
    const float* __restrict__ times, const int* __restrict__ time_ptr,
    const float* __restrict__ X, const int* __restrict__ M,
    const int* __restrict__ obs_idx,
    const float* __restrict__ W0, const float* __restrict__ b0,
    const float* __restrict__ W1, const float* __restrict__ b1,
    const float* __restrict__ W2, const float* __restrict__ b2,
    const float* __restrict__ Wq, const float* __restrict__ bq,
    const float* __restrict__ Wk,
    int* __restrict__ lens,
    ushort* __restrict__ W0p, ushort* __restrict__ W1b, ushort* __restrict__ W2b,
    ushort* __restrict__ feat_g, float* __restrict__ r_all)
{
  const int b = blockIdx.x;
  const int t = threadIdx.x;
  if (b >= B_PAT) {
    if (b == B_PAT) {
      for (int i = t; i < HW * NIN; i += 512) {
        int n = i >> 6, k = i & 63;
        W0p[i] = (k < 34) ? f2b(W0[n * 34 + k]) : (ushort)0;
      }
    } else if (b == B_PAT + 1) {
      for (int i = t; i < HW * HW; i += 512) W1b[i] = f2b(W1[i]);
    } else {
      for (int i = t; i < HW * HW; i += 512) W2b[i] = f2b(W2[i]);
    }
    return;
  }
  __shared__ int rs_s, re_s;
  __shared__ unsigned int umask_s[64];
  __shared__ int pbase_s[65];
  __shared__ float tval_s[64];
  __shared__ int qrc[3];
  __shared__ float x_s[64];
  __shared__ float inv_ts[NTS];
  __shared__ float hA[HW], hB[HW], part[512];
  // row range (parallel scan of obs_idx)
  {
    int r0 = t * 4;
#pragma unroll
    for (int j = 0; j < 4; ++j) {
      int r = r0 + j;
      if (obs_idx[r] == b) {
        if (r == 0 || obs_idx[r - 1] != b) rs_s = r;
        if (r == RTOT - 1 || obs_idx[r + 1] != b) re_s = r + 1;
      }
    }
  }
  if (t >= 496) inv_ts[t - 496] = 1.0f / tscale(t - 496);
  __syncthreads();
  const int rs = rs_s;
  const int n = re_s - rs;  // <= 64
  // wave 0: masks + counts + times + single-pass scan + q-row select
  if (t < 64) {
    unsigned int mk = 0;
    if (t < n) {
      const int4* mp = (const int4*)(M + (size_t)(rs + t) * NV);
#pragma unroll
      for (int q8 = 0; q8 < 8; ++q8) {
        int4 m4 = mp[q8];
        mk |= (m4.x != 0 ? 1u : 0u) << (q8 * 4);
        mk |= (m4.y != 0 ? 1u : 0u) << (q8 * 4 + 1);
        mk |= (m4.z != 0 ? 1u : 0u) << (q8 * 4 + 2);
        mk |= (m4.w != 0 ? 1u : 0u) << (q8 * 4 + 3);
      }
      int lo = 0, hi = RTOT - 1, r = rs + t;
      while (lo < hi) { int mid = (lo + hi + 1) >> 1; if (time_ptr[mid] <= r) lo = mid; else hi = mid - 1; }
      tval_s[t] = times[lo];
    }
    umask_s[t] = mk;
    int incl = __popc(mk);
#pragma unroll
    for (int off = 1; off < 64; off <<= 1) {
      int v = __shfl_up(incl, off);
      if (t >= off) incl += v;
    }
    pbase_s[t + 1] = incl;
    if (t == 0) pbase_s[0] = 0;
    // q-row (position LMAX-1): ballot row-select + shfl gather
    unsigned long long bal = __ballot(incl <= LMAX - 1);
    int len_w = __shfl(incl, 63);
    int lr0 = __popcll(bal);
    int pb_lr = __shfl(incl, lr0 - 1);
    int mk_lr = __shfl((int)mk, lr0 & 63);
    if (t == 0) {
      lens[b] = len_w;
      if (LMAX - 1 < len_w) {
        int k = (LMAX - 1) - pb_lr;
        unsigned int m = (unsigned int)mk_lr;
        for (int i = 0; i < k; ++i) m &= m - 1;
        qrc[0] = lr0; qrc[1] = (m != 0u) ? __builtin_ctz(m) : 0; qrc[2] = 1;
      } else qrc[2] = 0;
    }
  }
  __syncthreads();
  const int len = pbase_s[64];
  // feature build: all per-position work, once per patient (64 pos/iter)
  {
    ushort* featb = feat_g + (size_t)b * LMAX * NIN;
    for (int p0 = 0; p0 < len; p0 += 64) {
      int pos = p0 + (t >> 3), sub = t & 7;
      if (pos < len) {
        unsigned int* dst = (unsigned int*)(featb + (size_t)pos * NIN);
        if (sub < 5) {
          int lo = 0, hi = 63;
          while (lo < hi) { int mid = (lo + hi + 1) >> 1; if (pbase_s[mid] <= pos) lo = mid; else hi = mid - 1; }
          int lrow = lo;
          int rank = pos - pbase_s[lrow];
          unsigned int m = umask_s[lrow];
          for (int i = 0; i < rank; ++i) m &= m - 1;
          int col = (m != 0u) ? __builtin_ctz(m) : 0;
          float tv = tval_s[lrow];
          if (sub < 2) {            // sin halves (dwords 0..7)
#pragma unroll
            for (int w = 0; w < 4; ++w) {
              int i0 = sub * 8 + 2 * w;
              dst[sub * 4 + w] = pack2(f2b(__sinf(tv * inv_ts[i0])), f2b(__sinf(tv * inv_ts[i0 + 1])));
            }
          } else if (sub < 4) {     // cos halves (dwords 8..15)
#pragma unroll
            for (int w = 0; w < 4; ++w) {
              int i0 = (sub - 2) * 8 + 2 * w;
              dst[8 + (sub - 2) * 4 + w] = pack2(f2b(__cosf(tv * inv_ts[i0])), f2b(__cosf(tv * inv_ts[i0 + 1])));
            }
          } else {                  // col/val (dword 16)
            dst[16] = pack2(f2b((float)col), f2b(X[(size_t)(rs + lrow) * NV + col]));
          }
        } else {                    // zero K-pad dwords 17..31
          int d0 = 17 + (sub - 5) * 5;
#pragma unroll
          for (int w = 0; w < 5; ++w) dst[d0 + w] = 0u;
        }
      }
    }
  }
  // q-row feature x
  if (t < 64) x_s[t] = 0.0f;
  __syncthreads();
  if (qrc[2] == 0) {
    if (t >= 16 && t < 32) x_s[t] = 1.0f;  // pad row: sin=0, cos=1, col=0, val=0
  } else {
    int lr = qrc[0], col = qrc[1];
    if (t < 16) {
      float a = tval_s[lr] / tscale(t);
      x_s[t] = sinf(a); x_s[16 + t] = cosf(a);
    }
    if (t == 0) { x_s[32] = (float)col; x_s[33] = X[(size_t)(rs + lr) * NV + col]; }
  }
  __syncthreads();
  // q-row GEMV chain (fp32), 4-way k-split across 512 threads
  if (t < HW) {
    float a = b0[t];
#pragma unroll 2
    for (int k = 0; k < 34; ++k) a += W0[t * 34 + k] * x_s[k];
    hA[t] = fmaxf(a, 0.0f);
  }
  __syncthreads();
  {
    int oo = t & 127, hf = t >> 7;
    float a = 0.f;
    const float* wr = W1 + oo * HW + hf * 32;
#pragma unroll 8
    for (int k = 0; k < 32; ++k) a += wr[k] * hA[hf * 32 + k];
    part[t] = a;
  }
  __syncthreads();
  if (t < HW) hB[t] = fmaxf(part[t] + part[t + 128] + part[t + 256] + part[t + 384] + b1[t], 0.0f);
  __syncthreads();
  {
    int oo = t & 127, hf = t >> 7;
    float a = 0.f;
    const float* wr = W2 + oo * HW + hf * 32;
#pragma unroll 8
    for (int k = 0; k < 32; ++k) a += wr[k] * hB[hf * 32 + k];
    part[t] = a;
  }
  __syncthreads();
  if (t < HW) hA[t] = part[t] + part[t + 128] + part[t + 256] + part[t + 384] + b2[t];  // eq
  __syncthreads();
  {
    int oo = t & 127, hf = t >> 7;
    float a = 0.f;
    const float* wr = Wq + oo * HW + hf * 32;
#pragma unroll 8
    for (int k = 0; k < 32; ++k) a += wr[k] * hA[hf * 32 + k];
    part[t] = a;
  }
  __syncthreads();
  if (t < HW) hB[t] = part[t] + part[t + 128] + part[t + 256] + part[t + 384] + bq[t];  // q
  __syncthreads();
  {
    const float scale = 0.17677669529663687f;
    int h = t >> 7, e = t & 127;
    float a = 0.f;
#pragma unroll 8
    for (int d = 0; d < 32; ++d) a += Wk[(h * 32 + d) * HW + e] * hB[h * 32 + d];
    r_all[b * 512 + t] = a * scale;
  }
}

// ---------------------------------------------------------------------------
// kF: block = (patient, uniform 63-position chunk), 512 threads (8 waves).
// Front-end is now a thin coalesced copy: feat rows (built in kP) -> LDS tile,
// r -> LDS. Then the R3-verified pipeline: layer0 -> layer1 -> layer2 ->
// logits -> softmax -> weighted sums. ~55 KB LDS -> 2 blocks/CU.
// ---------------------------------------------------------------------------
__global__ __launch_bounds__(512, 4) void kF(
    const int* __restrict__ lens,
    const ushort* __restrict__ W0p, const float* __restrict__ b0,
    const ushort* __restrict__ W1b, const float* __restrict__ b1,
    const ushort* __restrict__ W2b, const float* __restrict__ b2,
    const float* __restrict__ r_all, const ushort* __restrict__ feat_g,
    float* __restrict__ partial, float2* __restrict__ mxsm)
{
  const int bx = blockIdx.x;
  const int b = bx >> 4, c = bx & 15;
  const int t = threadIdx.x;
  const int len = lens[b];
  const int start = c * CH;
  int valid = len - start; if (valid > CH) valid = CH;
  if (valid <= 0) {
    if (t < 4) mxsm[bx * 4 + t] = make_float2(-1e30f, 0.0f);
    return;
  }
  __shared__ __align__(16) char smem[SM_TOTAL];
  ushort* tile = (ushort*)(smem + SM_R0);   // P0 copy -> layer0
  ushort* bufB = (ushort*)(smem + SM_R0);   // layer1 -> layer2 (tile dead)
  ushort* bufA = (ushort*)(smem + SM_R1);   // layer0 -> layer1
  float*  encs = (float*)(smem + SM_R1);    // layer2 -> logits/wsum (bufA dead)
  __shared__ float r_s[4 * RLD];
  __shared__ float lg[4 * 64];
  __shared__ float mx_s[4], sm_s[4];
  // P0: r load + feat tile copy (coalesced 16B) — one barrier
  r_s[(t >> 7) * RLD + (t & 127)] = r_all[b * 512 + t];
  {
    int pos = t >> 3, sub = t & 7;
    if (pos < valid)
      *(short8*)(tile + pos * TLD + sub * 8) =
          *(const short8*)(feat_g + ((size_t)b * LMAX + start + pos) * NIN + sub * 8);
  }
  const int wv = t >> 6, lane = t & 63;
  const int m16 = lane & 15, quad = lane >> 4;
  const int rg = wv & 3, nh = wv >> 2;      // row group / N-half
  const int rowl = rg * 16 + m16;
  // hoist layer-0 B-fragments + biases (issue before the barrier)
  short8 w0a[4], w0b[4]; float bz0[4];
#pragma unroll
  for (int nt = 0; nt < 4; ++nt) {
    int nn = nh * 64 + nt * 16 + m16;
    const short8* br = (const short8*)(W0p + nn * NIN);
    w0a[nt] = br[quad]; w0b[nt] = br[4 + quad];
    bz0[nt] = b0[nn];
  }
  __syncthreads();
  // layer 0: tile[.,64] @ W0p^T (K=64). Garbage rows >= valid are
  // row-contained through the MFMA layers and masked at logits/wsum.
  {
    const short8* ar = (const short8*)(tile + rowl * TLD);
    short8 a0 = ar[quad];
    short8 a1 = ar[4 + quad];
#pragma unroll
    for (int nt = 0; nt < 4; ++nt) {
      int nn = nh * 64 + nt * 16 + m16;
      floatx4 acc = {0.f, 0.f, 0.f, 0.f};
      acc = __builtin_amdgcn_mfma_f32_16x16x32_bf16(a0, w0a[nt], acc, 0, 0, 0);
      acc = __builtin_amdgcn_mfma_f32_16x16x32_bf16(a1, w0b[nt], acc, 0, 0, 0);
      float bias = bz0[nt];
#pragma unroll
      for (int i = 0; i < 4; ++i) {
        float vv = fmaxf(acc[i] + bias, 0.0f);
        bufA[(rg * 16 + quad * 4 + i) * LDSP + nn] = f2b(vv);
      }
    }
  }
  __syncthreads();
  // layer 1 (K=128): reads bufA, writes bufB (tile region — tile is dead)
  {
#pragma unroll
    for (int nt = 0; nt < 4; ++nt) {
      int nn = nh * 64 + nt * 16 + m16;
      floatx4 acc = {0.f, 0.f, 0.f, 0.f};
#pragma unroll
      for (int ks = 0; ks < 4; ++ks) {
        short8 a = *(const short8*)(bufA + rowl * LDSP + ks * 32 + quad * 8);
        short8 bb = *(const short8*)(W1b + nn * HW + ks * 32 + quad * 8);
        acc = __builtin_amdgcn_mfma_f32_16x16x32_bf16(a, bb, acc, 0, 0, 0);
      }
      float bias = b1[nn];
#pragma unroll
      for (int i = 0; i < 4; ++i) {
        float vv = fmaxf(acc[i] + bias, 0.0f);
        bufB[(rg * 16 + quad * 4 + i) * LDSP + nn] = f2b(vv);
      }
    }
  }
  __syncthreads();
  // layer 2 (K=128): reads bufB, writes encs fp32 (bufA region — bufA is dead)
  {
#pragma unroll
    for (int nt = 0; nt < 4; ++nt) {
      int nn = nh * 64 + nt * 16 + m16;
      floatx4 acc = {0.f, 0.f, 0.f, 0.f};
#pragma unroll
      for (int ks = 0; ks < 4; ++ks) {
        short8 a = *(const short8*)(bufB + rowl * LDSP + ks * 32 + quad * 8);
        short8 bb = *(const short8*)(W2b + nn * HW + ks * 32 + quad * 8);
        acc = __builtin_amdgcn_mfma_f32_16x16x32_bf16(a, bb, acc, 0, 0, 0);
      }
      float bias = b2[nn];
#pragma unroll
      for (int i = 0; i < 4; ++i)
        encs[(rg * 16 + quad * 4 + i) * ELD + nn] = acc[i] + bias;
    }
  }
  __syncthreads();
  // logits: all 512 threads — (m = t>>3, head = (t&7)>>1, half = t&1)
  {
    int m = t >> 3, hh = t & 7, h = hh >> 1, half = hh & 1;
    if (m < valid) {
      const float4* ev = (const float4*)(&encs[m * ELD + half * 64]);
      const float4* rv = (const float4*)(&r_s[h * RLD + half * 64]);
      float acc = 0.f;
#pragma unroll
      for (int e4 = 0; e4 < 16; ++e4) {
        float4 v = ev[e4], r = rv[e4];
        acc += v.x * r.x + v.y * r.y + v.z * r.z + v.w * r.w;
      }
      acc += __shfl_xor(acc, 1);
      if (half == 0) lg[h * 64 + m] = acc;
    }
  }
  __syncthreads();
  // local softmax per head (waves 0..3 = heads)
  if (wv < 4) {
    float v = (lane < valid) ? lg[wv * 64 + lane] : -1e30f;
    float mx = v;
#pragma unroll
    for (int o = 32; o >= 1; o >>= 1) mx = fmaxf(mx, __shfl_xor(mx, o));
    float p = (lane < valid) ? __expf(v - mx) : 0.f;
    lg[wv * 64 + lane] = p;
    float sm = p;
#pragma unroll
    for (int o = 32; o >= 1; o >>= 1) sm += __shfl_xor(sm, o);
    if (lane == 0) { mx_s[wv] = mx; sm_s[wv] = sm; }
  }
  __syncthreads();
  // partial weighted sums (unnormalized): 1 output per thread
  {
    int h = t >> 7, e = t & 127;
    float acc = 0.f;
    for (int m = 0; m < valid; ++m)
      acc += lg[h * 64 + m] * encs[m * ELD + e];
    partial[(size_t)bx * 512 + t] = acc;
  }
  if (t < 4) mxsm[bx * 4 + t] = make_float2(mx_s[t], sm_s[t]);
}

// ---------------------------------------------------------------------------
// kK: combine 16 chunks with online-softmax rescaling. 32 blocks x 512 thr.
// ---------------------------------------------------------------------------
__global__ __launch_bounds__(512) void kK(
    const float* __restrict__ partial, const float2* __restrict__ mxsm,
    float* __restrict__ out)
{
  const int b = blockIdx.x;
  const int t = threadIdx.x;
  __shared__ float f_s[NCH * 4];
  if (t < 4) {
    int h = t;
    float2 v[NCH];
    float M = -1e30f;
#pragma unroll
    for (int c = 0; c < NCH; ++c) {
      v[c] = mxsm[(b * NCH + c) * 4 + h];
      if (v[c].y > 0.f) M = fmaxf(M, v[c].x);
    }
    float S = 0.f;
#pragma unroll
    for (int c = 0; c < NCH; ++c)
      if (v[c].y > 0.f) S += v[c].y * expf(v[c].x - M);
    float invS = 1.0f / S;
#pragma unroll
    for (int c = 0; c < NCH; ++c)
      f_s[c * 4 + h] = (v[c].y > 0.f) ? expf(v[c].x - M) * invS : 0.f;
  }
  __syncthreads();
  {
    int h = t >> 7;
    float acc = 0.f;
#pragma unroll
    for (int c = 0; c < NCH; ++c) {
      float f = f_s[c * 4 + h];
      if (f > 0.f) acc += partial[((size_t)(b * NCH + c)) * 512 + t] * f;
    }
    out[b * 512 + t] = acc;
  }
}

extern "C" void kernel_launch(void* const* d_in, const int* in_sizes, int n_in,
                              void* d_out, int out_size, void* d_ws, size_t ws_size,
                              hipStream_t stream) {
  const float* times = (const float*)d_in[0];
  const int* time_ptr = (const int*)d_in[1];
  const float* X = (const float*)d_in[2];
  const int* M = (const int*)d_in[3];
  const int* obs_idx = (const int*)d_in[4];
  const float* W0 = (const float*)d_in[6];
  const float* b0 = (const float*)d_in[7];
  const float* W1 = (const float*)d_in[8];
  const float* b1 = (const float*)d_in[9];
  const float* W2 = (const float*)d_in[10];
  const float* b2 = (const float*)d_in[11];
  const float* Wq = (const float*)d_in[12];
  const float* bq = (const float*)d_in[13];
  const float* Wk = (const float*)d_in[14];
  // d_in[15] (bk) is softmax-invariant for the scores -> dropped.
  float* out = (float*)d_out;

  char* ws = (char*)d_ws;
  size_t off = 0;
  int* lens = (int*)(ws + off); off += 256;
  ushort* W0p = (ushort*)(ws + off); off += (size_t)HW * NIN * 2;     // 16 KB
  ushort* W1b = (ushort*)(ws + off); off += (size_t)HW * HW * 2;      // 32 KB
  ushort* W2b = (ushort*)(ws + off); off += (size_t)HW * HW * 2;      // 32 KB
  ushort* feat_g = (ushort*)(ws + off); off += (size_t)B_PAT * LMAX * NIN * 2; // ~4 MB
  float* r_all = (float*)(ws + off); off += (size_t)B_PAT * 512 * 4;  // 64 KB
  float* partial = (float*)(ws + off); off += (size_t)B_PAT * NCH * 512 * 4; // 1 MB
  float2* mxsm = (float2*)(ws + off); off += (size_t)B_PAT * NCH * 4 * 8;    // 16 KB

  kP<<<B_PAT + 3, 512, 0, stream>>>(times, time_ptr, X, M, obs_idx,
                                    W0, b0, W1, b1, W2, b2, Wq, bq, Wk,
                                    lens, W0p, W1b, W2b, feat_g, r_all);
  kF<<<B_PAT * NCH, 512, 0, stream>>>(lens, W0p, b0, W1b, b1, W2b, b2,
                                      r_all, feat_g, partial, mxsm);
  kK<<<B_PAT, 512, 0, stream>>>(partial, mxsm, out);
}

// Round 8
// 134.867 us; speedup vs baseline: 1.1857x; 1.1857x over previous
//
#include <hip/hip_runtime.h>

#define B_PAT 32
#define RTOT 2048
#define NV 32
#define LMAX 1008
#define NTS 16
#define NIN 64    // K-padded feature width (from 34)
#define TLD 72    // feature tile LDS row stride (ushorts)
#define HW 128    // MLP width / hidden
#define LDSP 136  // LDS row stride for MLP bufs (ushorts)
#define NCH 16    // position-chunks per patient
#define CH 63     // positions per chunk
#define ELD 132   // enc LDS stride (floats)
#define RLD 136   // r LDS stride (floats)

// LDS union offsets (bytes): region0 = tile (9216 B) U bufB (17408 B);
// region1 = bufA (17408 B) U encs (33792 B). Lifetimes:
//   tile: written P2, read layer0      | bufB: written layer1, read layer2
//   bufA: written layer0, read layer1  | encs: written layer2, read logits/wsum
// Barriers between each phase make the overlaps safe.
#define SM_R0 0
#define SM_R1 17408
#define SM_TOTAL (17408 + 33792)

typedef __attribute__((ext_vector_type(8))) short short8;
typedef __attribute__((ext_vector_type(4))) float floatx4;

__device__ __forceinline__ ushort f2b(float f) {
  unsigned int x = __float_as_uint(f);
  unsigned int r = (x + 0x7FFFu + ((x >> 16) & 1u)) >> 16;
  return (ushort)r;
}
__device__ __forceinline__ unsigned int pack2(ushort lo, ushort hi) {
  return (unsigned int)lo | ((unsigned int)hi << 16);
}
__device__ __forceinline__ float tscale(int i) {
  return exp2f((float)i * (6.643856189774724f / 15.0f)); // 100^(i/15)
}

// ---------------------------------------------------------------------------
// kP: blocks 0..31 (512 thr) — per-patient prep: row scan, masks+counts+times,
// single-pass prefix scan + ballot q-row select (no serial global loads),
// q-row fp32 GEMV chain with 4-way k-split (short reduce chains) -> r_all.
// blocks 32..34 — weight conversions to bf16 (W0 K-padded, W1, W2).
// ---------------------------------------------------------------------------
__global__ __launch_bounds__(512) void kP(
    const float* __restrict__ times, const int* __restrict__ time_ptr,
    const float* __restrict__ X, const int* __restrict__ M,
    const int* __restrict__ obs_idx,
    const float* __restrict__ W0, const float* __restrict__ b0,
    const float* __restrict__ W1, const float* __restrict__ b1,
    const float* __restrict__ W2, const float* __restrict__ b2,
    const float* __restrict__ Wq, const float* __restrict__ bq,
    const float* __restrict__ Wk,
    int* __restrict__ pbase_g, int* __restrict__ rowstart_g,
    int* __restrict__ lens, float* __restrict__ trow_g,
    ushort* __restrict__ W0p, ushort* __restrict__ W1b, ushort* __restrict__ W2b,
    float* __restrict__ r_all)
{
  const int b = blockIdx.x;
  const int t = threadIdx.x;
  if (b >= B_PAT) {
    if (b == B_PAT) {
      for (int i = t; i < HW * NIN; i += 512) {
        int n = i >> 6, k = i & 63;
        W0p[i] = (k < 34) ? f2b(W0[n * 34 + k]) : (ushort)0;
      }
    } else if (b == B_PAT + 1) {
      for (int i = t; i < HW * HW; i += 512) W1b[i] = f2b(W1[i]);
    } else {
      for (int i = t; i < HW * HW; i += 512) W2b[i] = f2b(W2[i]);
    }
    return;
  }
  __shared__ int rs_s, re_s;
  __shared__ int pbase_s[65];
  __shared__ float tval_s[64];
  __shared__ int qrc[3];
  __shared__ float x_s[64];
  __shared__ float hA[HW], hB[HW], part[512];
  // S0: row range (parallel scan of obs_idx)
  {
    int r0 = t * 4;
#pragma unroll
    for (int j = 0; j < 4; ++j) {
      int r = r0 + j;
      if (obs_idx[r] == b) {
        if (r == 0 || obs_idx[r - 1] != b) rs_s = r;
        if (r == RTOT - 1 || obs_idx[r + 1] != b) re_s = r + 1;
      }
    }
  }
  __syncthreads();
  const int rs = rs_s;
  const int n = re_s - rs;  // <= 64
  // S1 (wave 0): masks + counts + times + single-pass scan + ballot q-row
  if (t < 64) {
    unsigned int mk = 0;
    if (t < n) {
      const int4* mp = (const int4*)(M + (size_t)(rs + t) * NV);
#pragma unroll
      for (int q8 = 0; q8 < 8; ++q8) {
        int4 m4 = mp[q8];
        mk |= (m4.x != 0 ? 1u : 0u) << (q8 * 4);
        mk |= (m4.y != 0 ? 1u : 0u) << (q8 * 4 + 1);
        mk |= (m4.z != 0 ? 1u : 0u) << (q8 * 4 + 2);
        mk |= (m4.w != 0 ? 1u : 0u) << (q8 * 4 + 3);
      }
      int lo = 0, hi = RTOT - 1, r = rs + t;
      while (lo < hi) { int mid = (lo + hi + 1) >> 1; if (time_ptr[mid] <= r) lo = mid; else hi = mid - 1; }
      tval_s[t] = times[lo];
      trow_g[r] = times[lo];
    }
    int incl = __popc(mk);
#pragma unroll
    for (int off = 1; off < 64; off <<= 1) {
      int v = __shfl_up(incl, off);
      if (t >= off) incl += v;
    }
    pbase_s[t + 1] = incl;
    if (t == 0) pbase_s[0] = 0;
    // q-row (position LMAX-1): ballot row-select + shfl gather (no LDS RAW)
    unsigned long long bal = __ballot(incl <= LMAX - 1);
    int len_w = __shfl(incl, 63);
    int lr0 = __popcll(bal);
    int pb_lr = __shfl(incl, lr0 - 1);
    int mk_lr = __shfl((int)mk, lr0 & 63);
    if (t == 0) {
      rowstart_g[b] = rs; lens[b] = len_w;
      if (LMAX - 1 < len_w) {
        int k = (LMAX - 1) - pb_lr;
        unsigned int m = (unsigned int)mk_lr;
        for (int i = 0; i < k; ++i) m &= m - 1;   // drop k lowest set bits
        qrc[0] = lr0; qrc[1] = (m != 0u) ? __builtin_ctz(m) : 0; qrc[2] = 1;
      } else qrc[2] = 0;
    }
  }
  if (t >= 448 && t < 512) x_s[t - 448] = 0.0f;
  __syncthreads();
  if (t < 65) pbase_g[b * 65 + t] = pbase_s[t];
  // S2: build q-row feature x
  if (qrc[2] == 0) {
    if (t >= 16 && t < 32) x_s[t] = 1.0f;  // pad row: sin=0, cos=1, col=0, val=0
  } else {
    int lr = qrc[0], col = qrc[1];
    if (t < 16) {
      float a = tval_s[lr] / tscale(t);
      x_s[t] = sinf(a); x_s[16 + t] = cosf(a);
    }
    if (t == 0) { x_s[32] = (float)col; x_s[33] = X[(size_t)(rs + lr) * NV + col]; }
  }
  __syncthreads();
  // S3: q-row GEMV chain (fp32), 4-way k-split across 512 threads
  if (t < HW) {
    float a = b0[t];
#pragma unroll 2
    for (int k = 0; k < 34; ++k) a += W0[t * 34 + k] * x_s[k];
    hA[t] = fmaxf(a, 0.0f);
  }
  __syncthreads();
  {
    int oo = t & 127, hf = t >> 7;
    float a = 0.f;
    const float* wr = W1 + oo * HW + hf * 32;
#pragma unroll 8
    for (int k = 0; k < 32; ++k) a += wr[k] * hA[hf * 32 + k];
    part[t] = a;
  }
  __syncthreads();
  if (t < HW) hB[t] = fmaxf(part[t] + part[t + 128] + part[t + 256] + part[t + 384] + b1[t], 0.0f);
  __syncthreads();
  {
    int oo = t & 127, hf = t >> 7;
    float a = 0.f;
    const float* wr = W2 + oo * HW + hf * 32;
#pragma unroll 8
    for (int k = 0; k < 32; ++k) a += wr[k] * hB[hf * 32 + k];
    part[t] = a;
  }
  __syncthreads();
  if (t < HW) hA[t] = part[t] + part[t + 128] + part[t + 256] + part[t + 384] + b2[t];  // eq
  __syncthreads();
  {
    int oo = t & 127, hf = t >> 7;
    float a = 0.f;
    const float* wr = Wq + oo * HW + hf * 32;
#pragma unroll 8
    for (int k = 0; k < 32; ++k) a += wr[k] * hA[hf * 32 + k];
    part[t] = a;
  }
  __syncthreads();
  if (t < HW) hB[t] = part[t] + part[t + 128] + part[t + 256] + part[t + 384] + bq[t];  // q
  __syncthreads();
  {
    const float scale = 0.17677669529663687f;
    int h = t >> 7, e = t & 127;
    float a = 0.f;
#pragma unroll 8
    for (int d = 0; d < 32; ++d) a += Wk[(h * 32 + d) * HW + e] * hB[h * 32 + d];
    r_all[b * 512 + t] = a * scale;
  }
}

// ---------------------------------------------------------------------------
// kF: block = (patient, uniform 63-position chunk), 512 threads (8 waves).
// LDS unioned (~55 KB) -> 2 blocks/CU. W0p fragments + b0 hoisted to regs
// right after P0 so their global latency hides under P2's transcendentals.
// Logits phase uses all 512 threads (pairwise half-split + shfl reduce).
// [R3-verified structure — unchanged]
// ---------------------------------------------------------------------------
__global__ __launch_bounds__(512, 4) void kF(
    const int* __restrict__ M, const float* __restrict__ X,
    const int* __restrict__ pbase_g, const int* __restrict__ rowstart_g,
    const int* __restrict__ lens, const float* __restrict__ trow_g,
    const ushort* __restrict__ W0p, const float* __restrict__ b0,
    const ushort* __restrict__ W1b, const float* __restrict__ b1,
    const ushort* __restrict__ W2b, const float* __restrict__ b2,
    const float* __restrict__ r_all, float* __restrict__ partial,
    float2* __restrict__ mxsm)
{
  const int bx = blockIdx.x;
  const int b = bx >> 4, c = bx & 15;
  const int t = threadIdx.x;
  const int len = lens[b];
  const int start = c * CH;
  int valid = len - start; if (valid > CH) valid = CH;
  if (valid <= 0) {
    if (t < 4) mxsm[bx * 4 + t] = make_float2(-1e30f, 0.0f);
    return;
  }
  __shared__ __align__(16) char smem[SM_TOTAL];
  ushort* tile = (ushort*)(smem + SM_R0);   // P2 -> layer0
  ushort* bufB = (ushort*)(smem + SM_R0);   // layer1 -> layer2 (tile dead)
  ushort* bufA = (ushort*)(smem + SM_R1);   // layer0 -> layer1
  float*  encs = (float*)(smem + SM_R1);    // layer2 -> logits/wsum (bufA dead)
  __shared__ float r_s[4 * RLD];
  __shared__ float lg[4 * 64];
  __shared__ unsigned int umask[64];
  __shared__ float tval[64];
  __shared__ int pbase_s[65];
  __shared__ float inv_ts[NTS];
  __shared__ float mx_s[4], sm_s[4];
  const int rs = rowstart_g[b];
  // P0: r load + row masks + times + pbase + inv_ts (one barrier)
  r_s[(t >> 7) * RLD + (t & 127)] = r_all[b * 512 + t];
  if (t < 64) {
    const int4* mp = (const int4*)(M + (size_t)(rs + t) * NV);
    unsigned int mk = 0;
#pragma unroll
    for (int q8 = 0; q8 < 8; ++q8) {
      int4 m4 = mp[q8];
      mk |= (m4.x != 0 ? 1u : 0u) << (q8 * 4);
      mk |= (m4.y != 0 ? 1u : 0u) << (q8 * 4 + 1);
      mk |= (m4.z != 0 ? 1u : 0u) << (q8 * 4 + 2);
      mk |= (m4.w != 0 ? 1u : 0u) << (q8 * 4 + 3);
    }
    umask[t] = mk;
    tval[t] = trow_g[rs + t];
  } else if (t < 129) {
    pbase_s[t - 64] = pbase_g[b * 65 + (t - 64)];
  } else if (t >= 136 && t < 136 + NTS) {
    inv_ts[t - 136] = 1.0f / tscale(t - 136);
  }
  __syncthreads();
  const int wv = t >> 6, lane = t & 63;
  const int m16 = lane & 15, quad = lane >> 4;
  const int rg = wv & 3, nh = wv >> 2;      // row group / N-half
  const int rowl = rg * 16 + m16;
  // hoist layer-0 B-fragments + biases (global; independent of LDS phases) —
  // loads issue here, latency hides under P2's transcendental work
  short8 w0a[4], w0b[4]; float bz0[4];
#pragma unroll
  for (int nt = 0; nt < 4; ++nt) {
    int nn = nh * 64 + nt * 16 + m16;
    const short8* br = (const short8*)(W0p + nn * NIN);
    w0a[nt] = br[quad]; w0b[nt] = br[4 + quad];
    bz0[nt] = b0[nn];
  }
  // P2: feature fill — 8 threads per position; subs 5..7 zero K-pad dwords
  {
    int pos = t >> 3, sub = t & 7;
    if (pos < valid) {
      unsigned int* dst = (unsigned int*)(tile + pos * TLD);
      if (sub < 5) {
        int gpos = start + pos;
        int lo = 0, hi = 63;
        while (lo < hi) { int mid = (lo + hi + 1) >> 1; if (pbase_s[mid] <= gpos) lo = mid; else hi = mid - 1; }
        int lrow = lo;
        int rank = gpos - pbase_s[lrow];
        unsigned int m = umask[lrow];
        for (int i = 0; i < rank; ++i) m &= m - 1;
        int col = (m != 0u) ? __builtin_ctz(m) : 0;
        float tv = tval[lrow];
        if (sub < 2) {            // sin halves
#pragma unroll
          for (int w = 0; w < 4; ++w) {
            int i0 = sub * 8 + 2 * w;
            dst[sub * 4 + w] = pack2(f2b(__sinf(tv * inv_ts[i0])), f2b(__sinf(tv * inv_ts[i0 + 1])));
          }
        } else if (sub < 4) {     // cos halves
#pragma unroll
          for (int w = 0; w < 4; ++w) {
            int i0 = (sub - 2) * 8 + 2 * w;
            dst[8 + (sub - 2) * 4 + w] = pack2(f2b(__cosf(tv * inv_ts[i0])), f2b(__cosf(tv * inv_ts[i0 + 1])));
          }
        } else {                  // col/val
          dst[16] = pack2(f2b((float)col), f2b(X[(size_t)(rs + lrow) * NV + col]));
        }
      } else {                    // zero K-pad dwords 17..31
        int d0 = 17 + (sub - 5) * 5;
#pragma unroll
        for (int w = 0; w < 5; ++w) dst[d0 + w] = 0u;
      }
    }
  }
  __syncthreads();
  // layer 0: tile[.,64] @ W0p^T (K=64), B-fragments already in registers
  {
    const short8* ar = (const short8*)(tile + rowl * TLD);
    short8 a0 = ar[quad];
    short8 a1 = ar[4 + quad];
#pragma unroll
    for (int nt = 0; nt < 4; ++nt) {
      int nn = nh * 64 + nt * 16 + m16;
      floatx4 acc = {0.f, 0.f, 0.f, 0.f};
      acc = __builtin_amdgcn_mfma_f32_16x16x32_bf16(a0, w0a[nt], acc, 0, 0, 0);
      acc = __builtin_amdgcn_mfma_f32_16x16x32_bf16(a1, w0b[nt], acc, 0, 0, 0);
      float bias = bz0[nt];
#pragma unroll
      for (int i = 0; i < 4; ++i) {
        float vv = fmaxf(acc[i] + bias, 0.0f);
        bufA[(rg * 16 + quad * 4 + i) * LDSP + nn] = f2b(vv);
      }
    }
  }
  __syncthreads();
  // layer 1 (K=128): reads bufA, writes bufB (tile region — tile is dead)
  {
#pragma unroll
    for (int nt = 0; nt < 4; ++nt) {
      int nn = nh * 64 + nt * 16 + m16;
      floatx4 acc = {0.f, 0.f, 0.f, 0.f};
#pragma unroll
      for (int ks = 0; ks < 4; ++ks) {
        short8 a = *(const short8*)(bufA + rowl * LDSP + ks * 32 + quad * 8);
        short8 bb = *(const short8*)(W1b + nn * HW + ks * 32 + quad * 8);
        acc = __builtin_amdgcn_mfma_f32_16x16x32_bf16(a, bb, acc, 0, 0, 0);
      }
      float bias = b1[nn];
#pragma unroll
      for (int i = 0; i < 4; ++i) {
        float vv = fmaxf(acc[i] + bias, 0.0f);
        bufB[(rg * 16 + quad * 4 + i) * LDSP + nn] = f2b(vv);
      }
    }
  }
  __syncthreads();
  // layer 2 (K=128): reads bufB, writes encs fp32 (bufA region — bufA is dead)
  {
#pragma unroll
    for (int nt = 0; nt < 4; ++nt) {
      int nn = nh * 64 + nt * 16 + m16;
      floatx4 acc = {0.f, 0.f, 0.f, 0.f};
#pragma unroll
      for (int ks = 0; ks < 4; ++ks) {
        short8 a = *(const short8*)(bufB + rowl * LDSP + ks * 32 + quad * 8);
        short8 bb = *(const short8*)(W2b + nn * HW + ks * 32 + quad * 8);
        acc = __builtin_amdgcn_mfma_f32_16x16x32_bf16(a, bb, acc, 0, 0, 0);
      }
      float bias = b2[nn];
#pragma unroll
      for (int i = 0; i < 4; ++i)
        encs[(rg * 16 + quad * 4 + i) * ELD + nn] = acc[i] + bias;
    }
  }
  __syncthreads();
  // logits: all 512 threads — (m = t>>3, head = (t&7)>>1, half = t&1)
  {
    int m = t >> 3, hh = t & 7, h = hh >> 1, half = hh & 1;
    if (m < valid) {
      const float4* ev = (const float4*)(&encs[m * ELD + half * 64]);
      const float4* rv = (const float4*)(&r_s[h * RLD + half * 64]);
      float acc = 0.f;
#pragma unroll
      for (int e4 = 0; e4 < 16; ++e4) {
        float4 v = ev[e4], r = rv[e4];
        acc += v.x * r.x + v.y * r.y + v.z * r.z + v.w * r.w;
      }
      acc += __shfl_xor(acc, 1);
      if (half == 0) lg[h * 64 + m] = acc;
    }
  }
  __syncthreads();
  // local softmax per head (waves 0..3 = heads)
  if (wv < 4) {
    float v = (lane < valid) ? lg[wv * 64 + lane] : -1e30f;
    float mx = v;
#pragma unroll
    for (int o = 32; o >= 1; o >>= 1) mx = fmaxf(mx, __shfl_xor(mx, o));
    float p = (lane < valid) ? __expf(v - mx) : 0.f;
    lg[wv * 64 + lane] = p;
    float sm = p;
#pragma unroll
    for (int o = 32; o >= 1; o >>= 1) sm += __shfl_xor(sm, o);
    if (lane == 0) { mx_s[wv] = mx; sm_s[wv] = sm; }
  }
  __syncthreads();
  // partial weighted sums (unnormalized): 1 output per thread
  {
    int h = t >> 7, e = t & 127;
    float acc = 0.f;
    for (int m = 0; m < valid; ++m)
      acc += lg[h * 64 + m] * encs[m * ELD + e];
    partial[(size_t)bx * 512 + t] = acc;
  }
  if (t < 4) mxsm[bx * 4 + t] = make_float2(mx_s[t], sm_s[t]);
}

// ---------------------------------------------------------------------------
// kK: combine 16 chunks with online-softmax rescaling. 32 blocks x 512 thr,
// one output per thread. [R3-verified — unchanged]
// ---------------------------------------------------------------------------
__global__ __launch_bounds__(512) void kK(
    const float* __restrict__ partial, const float2* __restrict__ mxsm,
    float* __restrict__ out)
{
  const int b = blockIdx.x;
  const int t = threadIdx.x;
  __shared__ float f_s[NCH * 4];
  if (t < 4) {
    int h = t;
    float2 v[NCH];
    float M = -1e30f;
#pragma unroll
    for (int c = 0; c < NCH; ++c) {
      v[c] = mxsm[(b * NCH + c) * 4 + h];
      if (v[c].y > 0.f) M = fmaxf(M, v[c].x);
    }
    float S = 0.f;
#pragma unroll
    for (int c = 0; c < NCH; ++c)
      if (v[c].y > 0.f) S += v[c].y * expf(v[c].x - M);
    float invS = 1.0f / S;
#pragma unroll
    for (int c = 0; c < NCH; ++c)
      f_s[c * 4 + h] = (v[c].y > 0.f) ? expf(v[c].x - M) * invS : 0.f;
  }
  __syncthreads();
  {
    int h = t >> 7;
    float acc = 0.f;
#pragma unroll
    for (int c = 0; c < NCH; ++c) {
      float f = f_s[c * 4 + h];
      if (f > 0.f) acc += partial[((size_t)(b * NCH + c)) * 512 + t] * f;
    }
    out[b * 512 + t] = acc;
  }
}

extern "C" void kernel_launch(void* const* d_in, const int* in_sizes, int n_in,
                              void* d_out, int out_size, void* d_ws, size_t ws_size,
                              hipStream_t stream) {
  const float* times = (const float*)d_in[0];
  const int* time_ptr = (const int*)d_in[1];
  const float* X = (const float*)d_in[2];
  const int* M = (const int*)d_in[3];
  const int* obs_idx = (const int*)d_in[4];
  const float* W0 = (const float*)d_in[6];
  const float* b0 = (const float*)d_in[7];
  const float* W1 = (const float*)d_in[8];
  const float* b1 = (const float*)d_in[9];
  const float* W2 = (const float*)d_in[10];
  const float* b2 = (const float*)d_in[11];
  const float* Wq = (const float*)d_in[12];
  const float* bq = (const float*)d_in[13];
  const float* Wk = (const float*)d_in[14];
  // d_in[15] (bk) is softmax-invariant for the scores -> dropped.
  float* out = (float*)d_out;

  char* ws = (char*)d_ws;
  size_t off = 0;
  int* pbase_g = (int*)(ws + off); off += (size_t)B_PAT * 65 * 4;     // 8.3 KB
  int* rowstart_g = (int*)(ws + off); off += 256;
  int* lens = (int*)(ws + off); off += 256;
  float* trow_g = (float*)(ws + off); off += RTOT * 4;                // 8 KB
  ushort* W0p = (ushort*)(ws + off); off += (size_t)HW * NIN * 2;     // 16 KB
  ushort* W1b = (ushort*)(ws + off); off += (size_t)HW * HW * 2;      // 32 KB
  ushort* W2b = (ushort*)(ws + off); off += (size_t)HW * HW * 2;      // 32 KB
  float* r_all = (float*)(ws + off); off += (size_t)B_PAT * 512 * 4;  // 64 KB
  float* partial = (float*)(ws + off); off += (size_t)B_PAT * NCH * 512 * 4; // 1 MB
  float2* mxsm = (float2*)(ws + off); off += (size_t)B_PAT * NCH * 4 * 8;    // 16 KB

  kP<<<B_PAT + 3, 512, 0, stream>>>(times, time_ptr, X, M, obs_idx,
                                    W0, b0, W1, b1, W2, b2, Wq, bq, Wk,
                                    pbase_g, rowstart_g, lens, trow_g,
                                    W0p, W1b, W2b, r_all);
  kF<<<B_PAT * NCH, 512, 0, stream>>>(M, X, pbase_g, rowstart_g, lens, trow_g,
                                      W0p, b0, W1b, b1, W2b, b2, r_all,
                                      partial, mxsm);
  kK<<<B_PAT, 512, 0, stream>>>(partial, mxsm, out);
}